// Round 1
// baseline (846.273 us; speedup 1.0000x reference)
//
#include <hip/hip_runtime.h>
#include <math.h>

#define N_NODES 30000
#define N_EDGES 240000
#define E2 (N_EDGES + N_NODES)   // 270000 with self-loops
#define D 128
#define LAYERS 6
#define NEG_SLOPE 0.2f
#define LN_EPS 1e-5f

// ---------------- embedding lookup: h = emb[x]; xg = h ----------------
__global__ __launch_bounds__(256) void embed_kernel(const int* __restrict__ x,
        const float* __restrict__ emb, float* __restrict__ h, float* __restrict__ xg)
{
    int idx = blockIdx.x * 256 + threadIdx.x;       // float4 index over N*32
    if (idx >= N_NODES * 32) return;
    int n = idx >> 5, q = idx & 31;
    int xi = x[n];
    float4 v = ((const float4*)(emb + (size_t)xi * D))[q];
    ((float4*)h)[idx]  = v;
    ((float4*)xg)[idx] = v;
}

// ---------------- CSR build (by dst) ----------------
__global__ __launch_bounds__(256) void hist_kernel(const int* __restrict__ ei, int* __restrict__ cnt)
{
    int e = blockIdx.x * 256 + threadIdx.x;
    if (e >= E2) return;
    int d = (e < N_EDGES) ? ei[N_EDGES + e] : (e - N_EDGES);
    atomicAdd(&cnt[d], 1);
}

__global__ __launch_bounds__(1024) void scan_kernel(const int* __restrict__ cnt,
        int* __restrict__ row_off, int* __restrict__ cursor)
{
    __shared__ int wtot[16];
    int t = threadIdx.x, lane = t & 63, w = t >> 6;
    int carry = 0;
    if (t == 0) row_off[0] = 0;
    for (int base = 0; base < N_NODES; base += 1024) {
        int i = base + t;
        int v = (i < N_NODES) ? cnt[i] : 0;
        int s = v;
        #pragma unroll
        for (int off = 1; off < 64; off <<= 1) {
            int u = __shfl_up(s, off);
            if (lane >= off) s += u;
        }
        if (lane == 63) wtot[w] = s;
        __syncthreads();
        if (t < 16) {
            int xv = wtot[t];
            #pragma unroll
            for (int off = 1; off < 16; off <<= 1) {
                int u = __shfl_up(xv, off);
                if (t >= off) xv += u;
            }
            wtot[t] = xv;
        }
        __syncthreads();
        int wpref = (w == 0) ? 0 : wtot[w - 1];
        int inc = wpref + s;                 // inclusive prefix within chunk
        if (i < N_NODES) {
            row_off[i + 1] = carry + inc;
            cursor[i]      = carry + inc - v; // exclusive
        }
        carry += wtot[15];
        __syncthreads();
    }
}

__global__ __launch_bounds__(256) void scatter_kernel(const int* __restrict__ ei,
        int* __restrict__ cursor, int* __restrict__ csr_src)
{
    int e = blockIdx.x * 256 + threadIdx.x;
    if (e >= E2) return;
    int s, d;
    if (e < N_EDGES) { s = ei[e]; d = ei[N_EDGES + e]; }
    else             { s = e - N_EDGES; d = s; }
    int pos = atomicAdd(&cursor[d], 1);
    csr_src[pos] = s;
}

// ---------------- fp32 GEMM: C = (A [+A2]) @ W + bias,  K=Ncols=128 ----------------
// blockIdx.y selects (W0,b0,C0) vs (W1,b1,C1) so xl/xr are one launch.
#define FMA_ROW(ACC, AV)                                                         \
    ACC.x += AV.x * w0.x; ACC.y += AV.x * w0.y; ACC.z += AV.x * w0.z; ACC.w += AV.x * w0.w; \
    ACC.x += AV.y * w1.x; ACC.y += AV.y * w1.y; ACC.z += AV.y * w1.z; ACC.w += AV.y * w1.w; \
    ACC.x += AV.z * w2.x; ACC.y += AV.z * w2.y; ACC.z += AV.z * w2.z; ACC.w += AV.z * w2.w; \
    ACC.x += AV.w * w3.x; ACC.y += AV.w * w3.y; ACC.z += AV.w * w3.z; ACC.w += AV.w * w3.w;

__global__ __launch_bounds__(256) void gemm128(
    const float* __restrict__ A, const float* __restrict__ A2,
    const float* __restrict__ W0, const float* __restrict__ b0, float* __restrict__ C0,
    const float* __restrict__ W1, const float* __restrict__ b1, float* __restrict__ C1,
    int M)
{
    __shared__ float Ws[64 * 128];   // 32 KB k-slab of W
    __shared__ float As[32 * 128];   // 16 KB A tile
    const float* W    = blockIdx.y ? W1 : W0;
    const float* bias = blockIdx.y ? b1 : b0;
    float*       C    = blockIdx.y ? C1 : C0;
    int t = threadIdx.x;
    int m0 = blockIdx.x * 32;

    #pragma unroll
    for (int i = 0; i < 4; i++) {                  // 1024 float4 A-tile
        int idx = t + i * 256;
        int r = idx >> 5, q = idx & 31;
        int gr = m0 + r;
        float4 v = make_float4(0.f, 0.f, 0.f, 0.f);
        if (gr < M) {
            v = ((const float4*)(A + (size_t)gr * D))[q];
            if (A2) {
                float4 u = ((const float4*)(A2 + (size_t)gr * D))[q];
                v.x += u.x; v.y += u.y; v.z += u.z; v.w += u.w;
            }
        }
        ((float4*)As)[idx] = v;
    }

    int tx = t & 31, ty = t >> 5;                  // 32 col-groups x 8 row-groups
    float4 acc0 = make_float4(0,0,0,0), acc1 = acc0, acc2 = acc0, acc3 = acc0;

    for (int half = 0; half < 2; half++) {
        #pragma unroll
        for (int i = 0; i < 8; i++) {              // 2048 float4 W-slab
            int idx = t + i * 256;
            ((float4*)Ws)[idx] = ((const float4*)(W + half * 64 * D))[idx];
        }
        __syncthreads();
        #pragma unroll 4
        for (int kk = 0; kk < 64; kk += 4) {
            float4 a0 = *(const float4*)&As[(ty*4 + 0) * D + half*64 + kk];
            float4 a1 = *(const float4*)&As[(ty*4 + 1) * D + half*64 + kk];
            float4 a2 = *(const float4*)&As[(ty*4 + 2) * D + half*64 + kk];
            float4 a3 = *(const float4*)&As[(ty*4 + 3) * D + half*64 + kk];
            float4 w0 = *(const float4*)&Ws[(kk + 0) * D + tx*4];
            float4 w1 = *(const float4*)&Ws[(kk + 1) * D + tx*4];
            float4 w2 = *(const float4*)&Ws[(kk + 2) * D + tx*4];
            float4 w3 = *(const float4*)&Ws[(kk + 3) * D + tx*4];
            FMA_ROW(acc0, a0); FMA_ROW(acc1, a1); FMA_ROW(acc2, a2); FMA_ROW(acc3, a3);
        }
        __syncthreads();
    }

    float4 bv = ((const float4*)bias)[tx];
    float4 accs[4] = {acc0, acc1, acc2, acc3};
    #pragma unroll
    for (int i = 0; i < 4; i++) {
        int gr = m0 + ty * 4 + i;
        if (gr < M) {
            float4 o = accs[i];
            o.x += bv.x; o.y += bv.y; o.z += bv.z; o.w += bv.w;
            ((float4*)(C + (size_t)gr * D))[tx] = o;
        }
    }
}

// ---------------- fused GATv2 edge phase: online-softmax aggregation ----------------
// one wave per node; lane holds channels (2*lane, 2*lane+1)
__global__ __launch_bounds__(256) void gat_agg(
    const float* __restrict__ xl, const float* __restrict__ xr,
    const int* __restrict__ row_off, const int* __restrict__ csr_src,
    const float* __restrict__ att, const float* __restrict__ conv_bias,
    float* __restrict__ xg)
{
    int node = blockIdx.x * 4 + (threadIdx.x >> 6);
    int lane = threadIdx.x & 63;
    if (node >= N_NODES) return;
    float2 xrn = ((const float2*)(xr + (size_t)node * D))[lane];
    float2 av  = ((const float2*)att)[lane];
    int s0 = row_off[node], s1 = row_off[node + 1];
    float m = -1e30f, denom = 0.f;
    float2 acc = make_float2(0.f, 0.f);
    for (int s = s0; s < s1; s++) {
        int src = csr_src[s];
        float2 v = ((const float2*)(xl + (size_t)src * D))[lane];
        float tx = v.x + xrn.x, ty = v.y + xrn.y;
        tx = tx > 0.f ? tx : NEG_SLOPE * tx;
        ty = ty > 0.f ? ty : NEG_SLOPE * ty;
        float p = av.x * tx + av.y * ty;
        #pragma unroll
        for (int off = 32; off > 0; off >>= 1) p += __shfl_xor(p, off);
        float mn = fmaxf(m, p);
        float sc = __expf(m - mn);      // 0 on first edge (m=-1e30)
        float wv = __expf(p - mn);
        denom = denom * sc + wv;
        acc.x = acc.x * sc + wv * v.x;
        acc.y = acc.y * sc + wv * v.y;
        m = mn;
    }
    float2 cbv = ((const float2*)conv_bias)[lane];
    float inv = 1.f / denom;
    float2 o;
    o.x = acc.x * inv + cbv.x;
    o.y = acc.y * inv + cbv.y;
    ((float2*)(xg + (size_t)node * D))[lane] = o;
}

// ---------------- graph LayerNorm (global mean/var) ----------------
__global__ __launch_bounds__(256) void ln_reduce(const float* __restrict__ xg, float* __restrict__ acc)
{
    float s = 0.f, ss = 0.f;
    const int total4 = N_NODES * 32;
    for (int idx = blockIdx.x * 256 + threadIdx.x; idx < total4; idx += gridDim.x * 256) {
        float4 v = ((const float4*)xg)[idx];
        s  += v.x + v.y + v.z + v.w;
        ss += v.x*v.x + v.y*v.y + v.z*v.z + v.w*v.w;
    }
    #pragma unroll
    for (int off = 32; off > 0; off >>= 1) { s += __shfl_xor(s, off); ss += __shfl_xor(ss, off); }
    __shared__ float bs[4], bss[4];
    int w = threadIdx.x >> 6, lane = threadIdx.x & 63;
    if (lane == 0) { bs[w] = s; bss[w] = ss; }
    __syncthreads();
    if (threadIdx.x == 0) {
        atomicAdd(&acc[0], bs[0] + bs[1] + bs[2] + bs[3]);
        atomicAdd(&acc[1], bss[0] + bss[1] + bss[2] + bss[3]);
    }
}

__global__ __launch_bounds__(256) void ln_apply(float* __restrict__ xg, const float* __restrict__ acc,
        const float* __restrict__ g, const float* __restrict__ b)
{
    int idx = blockIdx.x * 256 + threadIdx.x;
    if (idx >= N_NODES * 32) return;
    const float invM = 1.f / (float)(N_NODES * D);
    float mu  = acc[0] * invM;
    float var = acc[1] * invM - mu * mu;
    float inv = rsqrtf(var + LN_EPS);
    int c4 = idx & 31;
    float4 gv = ((const float4*)g)[c4];
    float4 bv = ((const float4*)b)[c4];
    float4 v = ((float4*)xg)[idx];
    v.x = (v.x - mu) * inv * gv.x + bv.x; v.x = v.x > 0.f ? v.x : 0.f;
    v.y = (v.y - mu) * inv * gv.y + bv.y; v.y = v.y > 0.f ? v.y : 0.f;
    v.z = (v.z - mu) * inv * gv.z + bv.z; v.z = v.z > 0.f ? v.z : 0.f;
    v.w = (v.w - mu) * inv * gv.w + bv.w; v.w = v.w > 0.f ? v.w : 0.f;
    ((float4*)xg)[idx] = v;
}

// ---------------- BatchNorm1d (batch stats over rows) ----------------
__global__ __launch_bounds__(256) void bn_reduce(const float* __restrict__ out, float* __restrict__ acc)
{
    int c = threadIdx.x & 127;
    int rg = threadIdx.x >> 7;     // 0/1
    float s = 0.f, ss = 0.f;
    for (int r = blockIdx.x * 2 + rg; r < N_NODES; r += gridDim.x * 2) {
        float v = out[(size_t)r * D + c];
        s += v; ss += v * v;
    }
    __shared__ float ls[256], lss[256];
    ls[threadIdx.x] = s; lss[threadIdx.x] = ss;
    __syncthreads();
    if (rg == 0) {
        s  = ls[c]  + ls[c + 128];
        ss = lss[c] + lss[c + 128];
        atomicAdd(&acc[c], s);
        atomicAdd(&acc[128 + c], ss);
    }
}

__global__ __launch_bounds__(256) void bn_apply(float* __restrict__ out, const float* __restrict__ acc,
        const float* __restrict__ g, const float* __restrict__ b)
{
    int idx = blockIdx.x * 256 + threadIdx.x;
    if (idx >= N_NODES * 32) return;
    int c4 = idx & 31;
    const float invN = 1.f / (float)N_NODES;
    float4 s1 = ((const float4*)(acc))[c4];
    float4 s2 = ((const float4*)(acc + 128))[c4];
    float4 gv = ((const float4*)g)[c4];
    float4 bv = ((const float4*)b)[c4];
    float4 v = ((float4*)out)[idx];
    float mu, var, inv;
    mu = s1.x * invN; var = s2.x * invN - mu * mu; inv = rsqrtf(var + LN_EPS);
    v.x = (v.x - mu) * inv * gv.x + bv.x;
    mu = s1.y * invN; var = s2.y * invN - mu * mu; inv = rsqrtf(var + LN_EPS);
    v.y = (v.y - mu) * inv * gv.y + bv.y;
    mu = s1.z * invN; var = s2.z * invN - mu * mu; inv = rsqrtf(var + LN_EPS);
    v.z = (v.z - mu) * inv * gv.z + bv.z;
    mu = s1.w * invN; var = s2.w * invN - mu * mu; inv = rsqrtf(var + LN_EPS);
    v.w = (v.w - mu) * inv * gv.w + bv.w;
    ((float4*)out)[idx] = v;
}

extern "C" void kernel_launch(void* const* d_in, const int* in_sizes, int n_in,
                              void* d_out, int out_size, void* d_ws, size_t ws_size,
                              hipStream_t stream)
{
    const int*   x    = (const int*)d_in[0];
    const int*   ei   = (const int*)d_in[1];
    const float* emb  = (const float*)d_in[2];
    const float* Wl   = (const float*)d_in[3];
    const float* bl   = (const float*)d_in[4];
    const float* Wr   = (const float*)d_in[5];
    const float* br   = (const float*)d_in[6];
    const float* att  = (const float*)d_in[7];
    const float* cbias= (const float*)d_in[8];
    const float* lng  = (const float*)d_in[9];
    const float* lnb  = (const float*)d_in[10];
    const float* linW = (const float*)d_in[11];
    const float* linb = (const float*)d_in[12];
    const float* bng  = (const float*)d_in[13];
    const float* bnb  = (const float*)d_in[14];
    float* out = (float*)d_out;

    char* p = (char*)d_ws;
    float* h  = (float*)p; p += (size_t)N_NODES * D * 4;
    float* xg = (float*)p; p += (size_t)N_NODES * D * 4;
    float* xl = (float*)p; p += (size_t)N_NODES * D * 4;
    float* xr = (float*)p; p += (size_t)N_NODES * D * 4;
    int* cnt     = (int*)p; p += ((N_NODES * 4 + 255) / 256) * 256;
    int* row_off = (int*)p; p += (((N_NODES + 1) * 4 + 255) / 256) * 256;
    int* cursor  = (int*)p; p += ((N_NODES * 4 + 255) / 256) * 256;
    int* csr_src = (int*)p; p += ((E2 * 4 + 255) / 256) * 256;
    float* accs  = (float*)p; p += 2048;   // ln pairs at [0..9], bn at [16..271]

    hipMemsetAsync(cnt, 0, N_NODES * 4, stream);
    hipMemsetAsync(accs, 0, 2048, stream);

    embed_kernel<<<3750, 256, 0, stream>>>(x, emb, h, xg);
    hist_kernel<<<(E2 + 255) / 256, 256, 0, stream>>>(ei, cnt);
    scan_kernel<<<1, 1024, 0, stream>>>(cnt, row_off, cursor);
    scatter_kernel<<<(E2 + 255) / 256, 256, 0, stream>>>(ei, cursor, csr_src);

    for (int i = 0; i < LAYERS; i++) {
        gemm128<<<dim3(938, 2), 256, 0, stream>>>(xg, nullptr,
            Wl + (size_t)i * D * D, bl + i * D, xl,
            Wr + (size_t)i * D * D, br + i * D, xr, N_NODES);
        gat_agg<<<7500, 256, 0, stream>>>(xl, xr, row_off, csr_src,
            att + i * D, cbias + i * D, xg);
        if (i < LAYERS - 1) {
            ln_reduce<<<960, 256, 0, stream>>>(xg, accs + 2 * i);
            ln_apply<<<3750, 256, 0, stream>>>(xg, accs + 2 * i, lng + i * D, lnb + i * D);
        }
    }
    gemm128<<<dim3(938, 1), 256, 0, stream>>>(xg, h, linW, linb, out, linW, linb, out, N_NODES);
    bn_reduce<<<256, 256, 0, stream>>>(out, accs + 16);
    bn_apply<<<3750, 256, 0, stream>>>(out, accs + 16, bng, bnb);
}

// Round 2
// 641.107 us; speedup vs baseline: 1.3200x; 1.3200x over previous
//
#include <hip/hip_runtime.h>
#include <math.h>

#define N_NODES 30000
#define N_EDGES 240000
#define E2 (N_EDGES + N_NODES)   // 270000 with self-loops
#define D 128
#define LAYERS 6
#define NEG_SLOPE 0.2f
#define LN_EPS 1e-5f

typedef unsigned short u16;
typedef unsigned int u32;
using bfrag = __attribute__((ext_vector_type(8))) short;
using f32x4 = __attribute__((ext_vector_type(4))) float;

__device__ inline u16 f2bf(float f) {
    u32 u = __float_as_uint(f);
    u32 r = u + 0x7fffu + ((u >> 16) & 1u);
    return (u16)(r >> 16);
}
__device__ inline u32 bfadd2(u32 a, u32 b) {   // packed 2xbf16 + 2xbf16 -> packed 2xbf16
    float alo = __uint_as_float(a << 16), ahi = __uint_as_float(a & 0xffff0000u);
    float blo = __uint_as_float(b << 16), bhi = __uint_as_float(b & 0xffff0000u);
    return (u32)f2bf(alo + blo) | ((u32)f2bf(ahi + bhi) << 16);
}

// ---------------- weight prep: Wt[b][n][k] = bf16(W[b][k][n]) ----------------
__global__ __launch_bounds__(256) void wt_convert(const float* __restrict__ Wl,
        const float* __restrict__ Wr, const float* __restrict__ linW, u16* __restrict__ wt)
{
    __shared__ u16 tile[128 * 129];
    int b = blockIdx.x;
    const float* src = (b == 12) ? linW
                     : ((b & 1) ? Wr + (size_t)(b >> 1) * 16384 : Wl + (size_t)(b >> 1) * 16384);
    int t = threadIdx.x;
    #pragma unroll 4
    for (int i = 0; i < 64; i++) {
        int idx = t + 256 * i;           // idx = k*128 + n
        int k = idx >> 7, n = idx & 127;
        tile[n * 129 + k] = f2bf(src[idx]);
    }
    __syncthreads();
    u16* dst = wt + (size_t)b * 16384;
    #pragma unroll 4
    for (int i = 0; i < 64; i++) {
        int idx = t + 256 * i;           // idx = n*128 + k
        int n = idx >> 7, k = idx & 127;
        dst[idx] = tile[n * 129 + k];
    }
}

// ---------------- embedding lookup: xg_bf = h_bf = bf16(emb[x]) ----------------
__global__ __launch_bounds__(256) void embed_kernel(const int* __restrict__ x,
        const float* __restrict__ emb, u16* __restrict__ xg_bf, u16* __restrict__ h_bf)
{
    int idx = blockIdx.x * 256 + threadIdx.x;       // float4 index over N*32
    if (idx >= N_NODES * 32) return;
    int n = idx >> 5, q = idx & 31;
    float4 v = ((const float4*)(emb + (size_t)x[n] * D))[q];
    ushort4 o;
    o.x = f2bf(v.x); o.y = f2bf(v.y); o.z = f2bf(v.z); o.w = f2bf(v.w);
    ((ushort4*)xg_bf)[idx] = o;
    ((ushort4*)h_bf)[idx]  = o;
}

// ---------------- CSR build (by dst) ----------------
__global__ __launch_bounds__(256) void hist_kernel(const int* __restrict__ ei, int* __restrict__ cnt)
{
    int e = blockIdx.x * 256 + threadIdx.x;
    if (e >= E2) return;
    int d = (e < N_EDGES) ? ei[N_EDGES + e] : (e - N_EDGES);
    atomicAdd(&cnt[d], 1);
}

__global__ __launch_bounds__(1024) void scan_kernel(const int* __restrict__ cnt,
        int* __restrict__ row_off, int* __restrict__ cursor)
{
    __shared__ int wtot[16];
    int t = threadIdx.x, lane = t & 63, w = t >> 6;
    int carry = 0;
    if (t == 0) row_off[0] = 0;
    for (int base = 0; base < N_NODES; base += 1024) {
        int i = base + t;
        int v = (i < N_NODES) ? cnt[i] : 0;
        int s = v;
        #pragma unroll
        for (int off = 1; off < 64; off <<= 1) {
            int u = __shfl_up(s, off);
            if (lane >= off) s += u;
        }
        if (lane == 63) wtot[w] = s;
        __syncthreads();
        if (t < 16) {
            int xv = wtot[t];
            #pragma unroll
            for (int off = 1; off < 16; off <<= 1) {
                int u = __shfl_up(xv, off);
                if (t >= off) xv += u;
            }
            wtot[t] = xv;
        }
        __syncthreads();
        int wpref = (w == 0) ? 0 : wtot[w - 1];
        int inc = wpref + s;
        if (i < N_NODES) {
            row_off[i + 1] = carry + inc;
            cursor[i]      = carry + inc - v;
        }
        carry += wtot[15];
        __syncthreads();
    }
}

__global__ __launch_bounds__(256) void scatter_kernel(const int* __restrict__ ei,
        int* __restrict__ cursor, int* __restrict__ csr_src)
{
    int e = blockIdx.x * 256 + threadIdx.x;
    if (e >= E2) return;
    int s, d;
    if (e < N_EDGES) { s = ei[e]; d = ei[N_EDGES + e]; }
    else             { s = e - N_EDGES; d = s; }
    int pos = atomicAdd(&cursor[d], 1);
    csr_src[pos] = s;
}

// ---------------- bf16 MFMA GEMM: C1 = (A[+A2]) @ W1t^T + b1 (and C2 set) ----------------
// 32-row M-tile per block, 4 waves x 32 cols. B frags in registers from global (L2).
__global__ __launch_bounds__(256) void gemm_mfma(
    const u16* __restrict__ Abf, const u16* __restrict__ A2bf,
    const u16* __restrict__ Wt1, const float* __restrict__ b1, float* __restrict__ C1,
    const u16* __restrict__ Wt2, const float* __restrict__ b2, float* __restrict__ C2,
    int M)
{
    __shared__ u16 As[32 * 136];     // padded row stride 136 -> 2-way (free) LDS conflicts
    int t = threadIdx.x;
    int m0 = blockIdx.x * 32;
    int lane = t & 63, w = t >> 6;
    int n16 = lane & 15, quad = lane >> 4;
    int c0 = w * 32;
    bool dual = (Wt2 != nullptr);

    // B fragments: Wt layout [n][k]; frag = Wt[n][ks*32 + quad*8 .. +8]
    bfrag bW1[2][4], bW2[2][4];
    #pragma unroll
    for (int c = 0; c < 2; c++)
        #pragma unroll
        for (int ks = 0; ks < 4; ks++)
            bW1[c][ks] = *(const bfrag*)(Wt1 + (size_t)(c0 + c * 16 + n16) * 128 + ks * 32 + quad * 8);
    if (dual) {
        #pragma unroll
        for (int c = 0; c < 2; c++)
            #pragma unroll
            for (int ks = 0; ks < 4; ks++)
                bW2[c][ks] = *(const bfrag*)(Wt2 + (size_t)(c0 + c * 16 + n16) * 128 + ks * 32 + quad * 8);
    }

    // stage 32x128 bf16 A-tile
    #pragma unroll
    for (int i = 0; i < 2; i++) {
        int idx = t + 256 * i;           // 512 chunks of 16B
        int row = idx >> 4, c16 = idx & 15;
        int gr = m0 + row;
        uint4 v = make_uint4(0u, 0u, 0u, 0u);
        if (gr < M) {
            v = ((const uint4*)(Abf + (size_t)gr * 128))[c16];
            if (A2bf) {
                uint4 u = ((const uint4*)(A2bf + (size_t)gr * 128))[c16];
                v.x = bfadd2(v.x, u.x); v.y = bfadd2(v.y, u.y);
                v.z = bfadd2(v.z, u.z); v.w = bfadd2(v.w, u.w);
            }
        }
        *(uint4*)&As[row * 136 + c16 * 8] = v;
    }
    __syncthreads();

    f32x4 zero = {0.f, 0.f, 0.f, 0.f};
    f32x4 acc1[2][2] = {{zero, zero}, {zero, zero}};
    f32x4 acc2[2][2] = {{zero, zero}, {zero, zero}};
    #pragma unroll
    for (int ks = 0; ks < 4; ks++) {
        bfrag a[2];
        #pragma unroll
        for (int r = 0; r < 2; r++)
            a[r] = *(const bfrag*)&As[(r * 16 + n16) * 136 + ks * 32 + quad * 8];
        #pragma unroll
        for (int r = 0; r < 2; r++)
            #pragma unroll
            for (int c = 0; c < 2; c++) {
                acc1[r][c] = __builtin_amdgcn_mfma_f32_16x16x32_bf16(a[r], bW1[c][ks], acc1[r][c], 0, 0, 0);
                if (dual)
                    acc2[r][c] = __builtin_amdgcn_mfma_f32_16x16x32_bf16(a[r], bW2[c][ks], acc2[r][c], 0, 0, 0);
            }
    }

    float bv1[2] = { b1[c0 + n16], b1[c0 + 16 + n16] };
    #pragma unroll
    for (int r = 0; r < 2; r++)
        #pragma unroll
        for (int c = 0; c < 2; c++)
            #pragma unroll
            for (int reg = 0; reg < 4; reg++) {
                int grow = m0 + r * 16 + quad * 4 + reg;
                if (grow < M)
                    C1[(size_t)grow * 128 + c0 + c * 16 + n16] = acc1[r][c][reg] + bv1[c];
            }
    if (dual) {
        float bv2[2] = { b2[c0 + n16], b2[c0 + 16 + n16] };
        #pragma unroll
        for (int r = 0; r < 2; r++)
            #pragma unroll
            for (int c = 0; c < 2; c++)
                #pragma unroll
                for (int reg = 0; reg < 4; reg++) {
                    int grow = m0 + r * 16 + quad * 4 + reg;
                    if (grow < M)
                        C2[(size_t)grow * 128 + c0 + c * 16 + n16] = acc2[r][c][reg] + bv2[c];
                }
    }
}

// ---------------- fused GATv2 edge phase: 2 edges in flight per wave ----------------
// 32-lane half processes one edge; lane holds channels 4q..4q+3; halves merged at end.
__global__ __launch_bounds__(256) void gat_agg(
    const float* __restrict__ xl, const float* __restrict__ xr,
    const int* __restrict__ row_off, const int* __restrict__ csr_src,
    const float* __restrict__ att, const float* __restrict__ conv_bias,
    float* __restrict__ xg, u16* __restrict__ xg_bf)
{
    int node = blockIdx.x * 4 + (threadIdx.x >> 6);
    int lane = threadIdx.x & 63;
    int hl = lane >> 5, q = lane & 31;
    if (node >= N_NODES) return;
    float4 xrn = ((const float4*)(xr + (size_t)node * D))[q];
    float4 av  = ((const float4*)att)[q];
    int s0 = row_off[node], s1 = row_off[node + 1];
    int iters = (s1 - s0 + 1) >> 1;
    float m = -3e38f, denom = 0.f;
    float4 acc = make_float4(0.f, 0.f, 0.f, 0.f);
    for (int it = 0; it < iters; ++it) {
        int s = s0 + it * 2 + hl;
        bool ok = s < s1;
        int src = csr_src[ok ? s : s1 - 1];
        float4 v = ((const float4*)(xl + (size_t)src * D))[q];
        float tx = v.x + xrn.x, ty = v.y + xrn.y, tz = v.z + xrn.z, tw = v.w + xrn.w;
        tx = tx > 0.f ? tx : NEG_SLOPE * tx;
        ty = ty > 0.f ? ty : NEG_SLOPE * ty;
        tz = tz > 0.f ? tz : NEG_SLOPE * tz;
        tw = tw > 0.f ? tw : NEG_SLOPE * tw;
        float p = av.x * tx + av.y * ty + av.z * tz + av.w * tw;
        #pragma unroll
        for (int off = 16; off > 0; off >>= 1) p += __shfl_xor(p, off);
        if (!ok) p = -3e38f;
        float mn = fmaxf(m, p);
        float sc = __expf(m - mn);
        float wv = __expf(p - mn);
        denom = denom * sc + wv;
        acc.x = acc.x * sc + wv * v.x;
        acc.y = acc.y * sc + wv * v.y;
        acc.z = acc.z * sc + wv * v.z;
        acc.w = acc.w * sc + wv * v.w;
        m = mn;
    }
    // merge the two half-wave online-softmax states
    float m2 = __shfl_xor(m, 32);
    float d2 = __shfl_xor(denom, 32);
    float ax = __shfl_xor(acc.x, 32), ay = __shfl_xor(acc.y, 32);
    float az = __shfl_xor(acc.z, 32), aw = __shfl_xor(acc.w, 32);
    float mn = fmaxf(m, m2);
    float sA = __expf(m - mn), sB = __expf(m2 - mn);
    denom = denom * sA + d2 * sB;
    acc.x = acc.x * sA + ax * sB;
    acc.y = acc.y * sA + ay * sB;
    acc.z = acc.z * sA + az * sB;
    acc.w = acc.w * sA + aw * sB;
    float4 cb = ((const float4*)conv_bias)[q];
    float inv = 1.f / denom;
    float4 o;
    o.x = acc.x * inv + cb.x; o.y = acc.y * inv + cb.y;
    o.z = acc.z * inv + cb.z; o.w = acc.w * inv + cb.w;
    if (xg_bf) {            // last layer: bf16 only (feeds final MFMA GEMM)
        if (hl == 1) {
            ushort4 ob;
            ob.x = f2bf(o.x); ob.y = f2bf(o.y); ob.z = f2bf(o.z); ob.w = f2bf(o.w);
            ((ushort4*)(xg_bf + (size_t)node * D))[q] = ob;
        }
    } else {                // layers 0..4: fp32 (feeds LayerNorm)
        if (hl == 0) ((float4*)(xg + (size_t)node * D))[q] = o;
    }
}

// ---------------- graph LayerNorm (global mean/var) ----------------
__global__ __launch_bounds__(256) void ln_reduce(const float* __restrict__ xg, float* __restrict__ acc)
{
    float s = 0.f, ss = 0.f;
    const int total4 = N_NODES * 32;
    for (int idx = blockIdx.x * 256 + threadIdx.x; idx < total4; idx += gridDim.x * 256) {
        float4 v = ((const float4*)xg)[idx];
        s  += v.x + v.y + v.z + v.w;
        ss += v.x * v.x + v.y * v.y + v.z * v.z + v.w * v.w;
    }
    #pragma unroll
    for (int off = 32; off > 0; off >>= 1) { s += __shfl_xor(s, off); ss += __shfl_xor(ss, off); }
    __shared__ float bs[4], bss[4];
    int w = threadIdx.x >> 6, lane = threadIdx.x & 63;
    if (lane == 0) { bs[w] = s; bss[w] = ss; }
    __syncthreads();
    if (threadIdx.x == 0) {
        atomicAdd(&acc[0], bs[0] + bs[1] + bs[2] + bs[3]);
        atomicAdd(&acc[1], bss[0] + bss[1] + bss[2] + bss[3]);
    }
}

__global__ __launch_bounds__(256) void ln_apply(float* __restrict__ xg, const float* __restrict__ acc,
        const float* __restrict__ g, const float* __restrict__ b, u16* __restrict__ xg_bf)
{
    int idx = blockIdx.x * 256 + threadIdx.x;
    if (idx >= N_NODES * 32) return;
    const float invM = 1.f / (float)(N_NODES * D);
    float mu  = acc[0] * invM;
    float var = acc[1] * invM - mu * mu;
    float inv = rsqrtf(var + LN_EPS);
    int c4 = idx & 31;
    float4 gv = ((const float4*)g)[c4];
    float4 bv = ((const float4*)b)[c4];
    float4 v = ((float4*)xg)[idx];
    v.x = (v.x - mu) * inv * gv.x + bv.x; v.x = v.x > 0.f ? v.x : 0.f;
    v.y = (v.y - mu) * inv * gv.y + bv.y; v.y = v.y > 0.f ? v.y : 0.f;
    v.z = (v.z - mu) * inv * gv.z + bv.z; v.z = v.z > 0.f ? v.z : 0.f;
    v.w = (v.w - mu) * inv * gv.w + bv.w; v.w = v.w > 0.f ? v.w : 0.f;
    ushort4 ob;
    ob.x = f2bf(v.x); ob.y = f2bf(v.y); ob.z = f2bf(v.z); ob.w = f2bf(v.w);
    ((ushort4*)xg_bf)[idx] = ob;
}

// ---------------- BatchNorm1d (batch stats over rows) ----------------
__global__ __launch_bounds__(256) void bn_reduce(const float* __restrict__ out, float* __restrict__ acc)
{
    int c = threadIdx.x & 127;
    int rg = threadIdx.x >> 7;
    float s = 0.f, ss = 0.f;
    for (int r = blockIdx.x * 2 + rg; r < N_NODES; r += gridDim.x * 2) {
        float v = out[(size_t)r * D + c];
        s += v; ss += v * v;
    }
    __shared__ float ls[256], lss[256];
    ls[threadIdx.x] = s; lss[threadIdx.x] = ss;
    __syncthreads();
    if (rg == 0) {
        s  = ls[c]  + ls[c + 128];
        ss = lss[c] + lss[c + 128];
        atomicAdd(&acc[c], s);
        atomicAdd(&acc[128 + c], ss);
    }
}

__global__ __launch_bounds__(256) void bn_apply(float* __restrict__ out, const float* __restrict__ acc,
        const float* __restrict__ g, const float* __restrict__ b)
{
    int idx = blockIdx.x * 256 + threadIdx.x;
    if (idx >= N_NODES * 32) return;
    int c4 = idx & 31;
    const float invN = 1.f / (float)N_NODES;
    float4 s1 = ((const float4*)(acc))[c4];
    float4 s2 = ((const float4*)(acc + 128))[c4];
    float4 gv = ((const float4*)g)[c4];
    float4 bv = ((const float4*)b)[c4];
    float4 v = ((float4*)out)[idx];
    float mu, var, inv;
    mu = s1.x * invN; var = s2.x * invN - mu * mu; inv = rsqrtf(var + LN_EPS);
    v.x = (v.x - mu) * inv * gv.x + bv.x;
    mu = s1.y * invN; var = s2.y * invN - mu * mu; inv = rsqrtf(var + LN_EPS);
    v.y = (v.y - mu) * inv * gv.y + bv.y;
    mu = s1.z * invN; var = s2.z * invN - mu * mu; inv = rsqrtf(var + LN_EPS);
    v.z = (v.z - mu) * inv * gv.z + bv.z;
    mu = s1.w * invN; var = s2.w * invN - mu * mu; inv = rsqrtf(var + LN_EPS);
    v.w = (v.w - mu) * inv * gv.w + bv.w;
    ((float4*)out)[idx] = v;
}

extern "C" void kernel_launch(void* const* d_in, const int* in_sizes, int n_in,
                              void* d_out, int out_size, void* d_ws, size_t ws_size,
                              hipStream_t stream)
{
    const int*   x    = (const int*)d_in[0];
    const int*   ei   = (const int*)d_in[1];
    const float* emb  = (const float*)d_in[2];
    const float* Wl   = (const float*)d_in[3];
    const float* bl   = (const float*)d_in[4];
    const float* Wr   = (const float*)d_in[5];
    const float* br   = (const float*)d_in[6];
    const float* att  = (const float*)d_in[7];
    const float* cbias= (const float*)d_in[8];
    const float* lng  = (const float*)d_in[9];
    const float* lnb  = (const float*)d_in[10];
    const float* linW = (const float*)d_in[11];
    const float* linb = (const float*)d_in[12];
    const float* bng  = (const float*)d_in[13];
    const float* bnb  = (const float*)d_in[14];
    float* out = (float*)d_out;

    char* p = (char*)d_ws;
    float* xg    = (float*)p; p += (size_t)N_NODES * D * 4;
    float* xl    = (float*)p; p += (size_t)N_NODES * D * 4;
    float* xr    = (float*)p; p += (size_t)N_NODES * D * 4;
    u16*   xg_bf = (u16*)p;   p += (size_t)N_NODES * D * 2;
    u16*   h_bf  = (u16*)p;   p += (size_t)N_NODES * D * 2;
    u16*   wt    = (u16*)p;   p += (size_t)13 * 16384 * 2;
    int* cnt     = (int*)p; p += ((N_NODES * 4 + 255) / 256) * 256;
    int* row_off = (int*)p; p += (((N_NODES + 1) * 4 + 255) / 256) * 256;
    int* cursor  = (int*)p; p += ((N_NODES * 4 + 255) / 256) * 256;
    int* csr_src = (int*)p; p += ((E2 * 4 + 255) / 256) * 256;
    float* accs  = (float*)p; p += 2048;   // ln pairs at [0..9], bn at [16..271]

    hipMemsetAsync(cnt, 0, N_NODES * 4, stream);
    hipMemsetAsync(accs, 0, 2048, stream);

    wt_convert<<<13, 256, 0, stream>>>(Wl, Wr, linW, wt);
    embed_kernel<<<3750, 256, 0, stream>>>(x, emb, xg_bf, h_bf);
    hist_kernel<<<(E2 + 255) / 256, 256, 0, stream>>>(ei, cnt);
    scan_kernel<<<1, 1024, 0, stream>>>(cnt, row_off, cursor);
    scatter_kernel<<<(E2 + 255) / 256, 256, 0, stream>>>(ei, cursor, csr_src);

    for (int i = 0; i < LAYERS; i++) {
        gemm_mfma<<<938, 256, 0, stream>>>(xg_bf, nullptr,
            wt + (size_t)(2 * i) * 16384, bl + i * D, xl,
            wt + (size_t)(2 * i + 1) * 16384, br + i * D, xr, N_NODES);
        gat_agg<<<7500, 256, 0, stream>>>(xl, xr, row_off, csr_src,
            att + i * D, cbias + i * D, xg,
            (i == LAYERS - 1) ? xg_bf : nullptr);
        if (i < LAYERS - 1) {
            ln_reduce<<<960, 256, 0, stream>>>(xg, accs + 2 * i);
            ln_apply<<<3750, 256, 0, stream>>>(xg, accs + 2 * i, lng + i * D, lnb + i * D, xg_bf);
        }
    }
    gemm_mfma<<<938, 256, 0, stream>>>(xg_bf, h_bf,
        wt + (size_t)12 * 16384, linb, out, nullptr, nullptr, nullptr, N_NODES);
    bn_reduce<<<256, 256, 0, stream>>>(out, accs + 16);
    bn_apply<<<3750, 256, 0, stream>>>(out, accs + 16, bng, bnb);
}